// Round 1
// baseline (167.901 us; speedup 1.0000x reference)
//
#include <hip/hip_runtime.h>
#include <hip/hip_bf16.h>

#define N 8192
#define F 256
#define KSPLIT 4

using s16x8 = __attribute__((ext_vector_type(8))) short;
using f32x4 = __attribute__((ext_vector_type(4))) float;

__device__ __forceinline__ unsigned short f2bf(float f) {
  unsigned int u = __float_as_uint(f);
  unsigned int r = u + 0x7fffu + ((u >> 16) & 1u);   // RNE
  return (unsigned short)(r >> 16);
}
__device__ __forceinline__ float bf2f(unsigned short u) {
  return __uint_as_float(((unsigned int)u) << 16);
}

// ---------------- k0: Wt[f][k] = bf16(W[k][f]) ----------------
__global__ __launch_bounds__(256) void k0_wt(const float* __restrict__ W,
                                             unsigned short* __restrict__ Wt) {
  int k = blockIdx.x;
  int f = threadIdx.x;
  Wt[f * 256 + k] = f2bf(W[k * 256 + f]);
}

// ---------------- k1: WhbT[f][j] = bf16( (h@W)[j][f] ) ----------------
// BM=64 rows/block, K=256 in 4 steps of 64. 4 waves, each 64x64 output.
__global__ __launch_bounds__(256) void k1_wh(const float* __restrict__ h,
                                             const unsigned short* __restrict__ Wt,
                                             unsigned short* __restrict__ WhbT) {
  __shared__ char lds[8192 + 32768];
  char* Alds = lds;           // 64 rows x 128B (bf16, XOR-swizzled)
  char* Blds = lds + 8192;    // 256 rows x 128B
  int t = threadIdx.x;
  int i0 = blockIdx.x * 64;
  int l = t & 63, w = t >> 6;
  int lr = l & 15, lk = l >> 4;
  f32x4 acc[4][4] = {};
  for (int kt = 0; kt < 4; ++kt) {
    int k0 = kt * 64;
    if (kt) __syncthreads();
    // A stage: h rows -> bf16
#pragma unroll
    for (int c = 0; c < 4; ++c) {
      int flat = c * 256 + t;
      int i = flat >> 4, jc = flat & 15;
      float4 v = *reinterpret_cast<const float4*>(h + (size_t)(i0 + i) * 256 + k0 + jc * 4);
      ushort4 pk;
      pk.x = f2bf(v.x); pk.y = f2bf(v.y); pk.z = f2bf(v.z); pk.w = f2bf(v.w);
      *reinterpret_cast<ushort4*>(Alds + i * 128 + ((jc * 8) ^ ((i & 7) << 4))) = pk;
    }
    // B stage: Wt tile
#pragma unroll
    for (int c = 0; c < 8; ++c) {
      int idx = c * 256 + t;
      int fr = idx >> 3, kc = idx & 7;
      uint4 v = *reinterpret_cast<const uint4*>(Wt + fr * 256 + k0 + kc * 8);
      *reinterpret_cast<uint4*>(Blds + fr * 128 + ((kc * 16) ^ ((fr & 7) << 4))) = v;
    }
    __syncthreads();
#pragma unroll
    for (int kk = 0; kk < 2; ++kk) {
      int kofs = kk * 64 + lk * 16;
      s16x8 afr[4], bfr[4];
#pragma unroll
      for (int mf = 0; mf < 4; ++mf) {
        int ar = mf * 16 + lr;
        afr[mf] = *reinterpret_cast<const s16x8*>(Alds + ar * 128 + (kofs ^ ((ar & 7) << 4)));
      }
#pragma unroll
      for (int nf = 0; nf < 4; ++nf) {
        int br = w * 64 + nf * 16 + lr;
        bfr[nf] = *reinterpret_cast<const s16x8*>(Blds + br * 128 + (kofs ^ ((br & 7) << 4)));
      }
#pragma unroll
      for (int mf = 0; mf < 4; ++mf)
#pragma unroll
        for (int nf = 0; nf < 4; ++nf)
          acc[mf][nf] = __builtin_amdgcn_mfma_f32_16x16x32_bf16(afr[mf], bfr[nf], acc[mf][nf], 0, 0, 0);
    }
  }
  // epilogue: C/D layout col=lane&15, row=(lane>>4)*4+r -> pack 4 consecutive j
#pragma unroll
  for (int mf = 0; mf < 4; ++mf) {
#pragma unroll
    for (int nf = 0; nf < 4; ++nf) {
      int f = w * 64 + nf * 16 + lr;
      int j = i0 + mf * 16 + lk * 4;
      ushort4 pk;
      pk.x = f2bf(acc[mf][nf][0]);
      pk.y = f2bf(acc[mf][nf][1]);
      pk.z = f2bf(acc[mf][nf][2]);
      pk.w = f2bf(acc[mf][nf][3]);
      *reinterpret_cast<ushort4*>(WhbT + (size_t)f * N + j) = pk;
    }
  }
}

// ---------------- k2: s1[j] = sum_f Wh[j][f]*a1[f]; s2 likewise ----------------
__global__ __launch_bounds__(256) void k2_s(const unsigned short* __restrict__ WhbT,
                                            const float* __restrict__ a,
                                            float* __restrict__ s1,
                                            float* __restrict__ s2) {
  int j = blockIdx.x * 256 + threadIdx.x;
  float acc1 = 0.f, acc2 = 0.f;
#pragma unroll 8
  for (int f = 0; f < 256; ++f) {
    float v = bf2f(WhbT[(size_t)f * N + j]);
    acc1 += v * a[f];
    acc2 += v * a[256 + f];
  }
  s1[j] = acc1;
  s2[j] = acc2;
}

// ---------------- k3: fused masked-softmax-weighted GEMM ----------------
// 128 rows x (N/KSPLIT) j-range per block; BK=64; 8 waves (2M x 4N), wave=64x64.
__global__ __launch_bounds__(512) void k3_attn(const float* __restrict__ adj,
                                               const unsigned short* __restrict__ WhbT,
                                               const float* __restrict__ s1,
                                               const float* __restrict__ s2,
                                               float* __restrict__ numw,
                                               float* __restrict__ denw) {
  __shared__ char lds[16384 + 32768 + 512];
  char* Alds = lds;                       // P tile: 128 x 128B
  char* Blds = lds + 16384;               // Wh tile: 256 x 128B
  float* denl = (float*)(lds + 16384 + 32768);
  int t = threadIdx.x;
  int ib = blockIdx.x;           // 0..63
  int ks = blockIdx.y;           // 0..KSPLIT-1
  int i0 = ib * 128;
  int jb = ks * (N / KSPLIT);
  int l = t & 63, w = t >> 6, wm = w >> 2, wn = w & 3;
  int lr = l & 15, lk = l >> 4;
  int g = t >> 4;                // 0..31: row group
  int jl = (t & 15) * 4;         // 4-float column chunk

  float s1v[4];
#pragma unroll
  for (int c = 0; c < 4; ++c) s1v[c] = s1[i0 + c * 32 + g];

  // adj register prefetch (iter 0)
  float4 aj[4];
#pragma unroll
  for (int c = 0; c < 4; ++c)
    aj[c] = *reinterpret_cast<const float4*>(adj + (size_t)(i0 + c * 32 + g) * N + jb + jl);

  float dsum[4] = {0.f, 0.f, 0.f, 0.f};
  f32x4 acc[4][4] = {};

  const int NIT = (N / KSPLIT) / 64;  // 32
  for (int it = 0; it < NIT; ++it) {
    int j0 = jb + it * 64;
    // issue B global loads early (L2 latency hidden by P-compute VALU)
    uint4 bv[4];
#pragma unroll
    for (int c = 0; c < 4; ++c) {
      int idx = c * 512 + t;
      int fr = idx >> 3, kc = idx & 7;
      bv[c] = *reinterpret_cast<const uint4*>(WhbT + (size_t)fr * N + j0 + kc * 8);
    }
    // P compute + A stage + denominator partials
    float4 s2v = *reinterpret_cast<const float4*>(s2 + j0 + jl);
#pragma unroll
    for (int c = 0; c < 4; ++c) {
      int i = c * 32 + g;
      float4 av = aj[c];
      float s1c = s1v[c];
      float x, p0, p1, p2, p3;
      x = s1c + s2v.x; x = x > 0.f ? x : 0.2f * x; p0 = av.x > 0.f ? __expf(x) : 0.f;
      x = s1c + s2v.y; x = x > 0.f ? x : 0.2f * x; p1 = av.y > 0.f ? __expf(x) : 0.f;
      x = s1c + s2v.z; x = x > 0.f ? x : 0.2f * x; p2 = av.z > 0.f ? __expf(x) : 0.f;
      x = s1c + s2v.w; x = x > 0.f ? x : 0.2f * x; p3 = av.w > 0.f ? __expf(x) : 0.f;
      ushort4 pk;
      pk.x = f2bf(p0); pk.y = f2bf(p1); pk.z = f2bf(p2); pk.w = f2bf(p3);
      // sum the *rounded* values so num/den are consistent
      dsum[c] += bf2f(pk.x) + bf2f(pk.y) + bf2f(pk.z) + bf2f(pk.w);
      *reinterpret_cast<ushort4*>(Alds + i * 128 + ((jl * 2) ^ ((i & 7) << 4))) = pk;
    }
    // B LDS writes
#pragma unroll
    for (int c = 0; c < 4; ++c) {
      int idx = c * 512 + t;
      int fr = idx >> 3, kc = idx & 7;
      *reinterpret_cast<uint4*>(Blds + fr * 128 + ((kc * 16) ^ ((fr & 7) << 4))) = bv[c];
    }
    __syncthreads();
    // prefetch next adj tile under MFMA
    if (it + 1 < NIT) {
      int j1 = j0 + 64;
#pragma unroll
      for (int c = 0; c < 4; ++c)
        aj[c] = *reinterpret_cast<const float4*>(adj + (size_t)(i0 + c * 32 + g) * N + j1 + jl);
    }
    // MFMA: 2 k-steps x 4x4 fragments
#pragma unroll
    for (int kk = 0; kk < 2; ++kk) {
      int kofs = kk * 64 + lk * 16;
      s16x8 afr[4], bfr[4];
#pragma unroll
      for (int mf = 0; mf < 4; ++mf) {
        int ar = wm * 64 + mf * 16 + lr;
        afr[mf] = *reinterpret_cast<const s16x8*>(Alds + ar * 128 + (kofs ^ ((ar & 7) << 4)));
      }
#pragma unroll
      for (int nf = 0; nf < 4; ++nf) {
        int br = wn * 64 + nf * 16 + lr;
        bfr[nf] = *reinterpret_cast<const s16x8*>(Blds + br * 128 + (kofs ^ ((br & 7) << 4)));
      }
#pragma unroll
      for (int mf = 0; mf < 4; ++mf)
#pragma unroll
        for (int nf = 0; nf < 4; ++nf)
          acc[mf][nf] = __builtin_amdgcn_mfma_f32_16x16x32_bf16(afr[mf], bfr[nf], acc[mf][nf], 0, 0, 0);
    }
    __syncthreads();
  }
  // denominator: reduce 16 lanes sharing a row
#pragma unroll
  for (int c = 0; c < 4; ++c) {
    float v = dsum[c];
    v += __shfl_xor(v, 1);
    v += __shfl_xor(v, 2);
    v += __shfl_xor(v, 4);
    v += __shfl_xor(v, 8);
    if ((t & 15) == 0) denl[c * 32 + g] = v;
  }
  __syncthreads();
  // write numerator partials
  float* nump = numw + (size_t)ks * N * F;
#pragma unroll
  for (int mf = 0; mf < 4; ++mf) {
#pragma unroll
    for (int nf = 0; nf < 4; ++nf) {
      int f = wn * 64 + nf * 16 + lr;
      int irow = i0 + wm * 64 + mf * 16 + lk * 4;
#pragma unroll
      for (int r = 0; r < 4; ++r)
        nump[(size_t)(irow + r) * F + f] = acc[mf][nf][r];
    }
  }
  if (t < 128) denw[(size_t)ks * N + i0 + t] = denl[t];
}

// ---------------- k4: combine K-splits, divide, elu ----------------
__global__ __launch_bounds__(256) void k4_fin(const float* __restrict__ numw,
                                              const float* __restrict__ denw,
                                              float* __restrict__ out) {
  int idx = blockIdx.x * 256 + threadIdx.x;
  int i = idx >> 8;
  float sn = 0.f, sd = 0.f;
#pragma unroll
  for (int ks = 0; ks < KSPLIT; ++ks) {
    sn += numw[(size_t)ks * N * F + idx];
    sd += denw[(size_t)ks * N + i];
  }
  float hp = sn / sd;
  out[idx] = hp > 0.f ? hp : (__expf(hp) - 1.f);
}

extern "C" void kernel_launch(void* const* d_in, const int* in_sizes, int n_in,
                              void* d_out, int out_size, void* d_ws, size_t ws_size,
                              hipStream_t stream) {
  const float* h   = (const float*)d_in[0];
  const float* adj = (const float*)d_in[1];
  const float* W   = (const float*)d_in[2];
  const float* a   = (const float*)d_in[3];
  float* out = (float*)d_out;

  char* ws = (char*)d_ws;
  unsigned short* WhbT = (unsigned short*)(ws);                       // 4 MB  [256][8192] bf16
  float* s1            = (float*)(ws + 4 * 1024 * 1024);              // 32 KB
  float* s2            = (float*)(ws + 4 * 1024 * 1024 + 32768);      // 32 KB
  float* denw          = (float*)(ws + 4 * 1024 * 1024 + 65536);      // 128 KB
  unsigned short* Wt   = (unsigned short*)(ws + 4 * 1024 * 1024 + 65536 + 131072);  // 128 KB
  float* numw          = (float*)(ws + 4 * 1024 * 1024 + 65536 + 131072 + 131072);  // 32 MB

  hipLaunchKernelGGL(k0_wt, dim3(256), dim3(256), 0, stream, W, Wt);
  hipLaunchKernelGGL(k1_wh, dim3(N / 64), dim3(256), 0, stream, h, Wt, WhbT);
  hipLaunchKernelGGL(k2_s, dim3(N / 256), dim3(256), 0, stream, WhbT, a, s1, s2);
  hipLaunchKernelGGL(k3_attn, dim3(64, KSPLIT), dim3(512), 0, stream,
                     adj, WhbT, s1, s2, numw, denw);
  hipLaunchKernelGGL(k4_fin, dim3(N * F / 256), dim3(256), 0, stream, numw, denw, out);
}